// Round 7
// baseline (712.596 us; speedup 1.0000x reference)
//
#include <hip/hip_runtime.h>

#define TWO_PI 6.28318530717958647692f

constexpr int BB   = 32;     // batch
constexpr int NTOT = 16384;  // sequence length
constexpr int CKd  = 16;     // C*K channels
constexpr int NLEV = 14;     // log2(NTOT)

// ===========================================================================
// BIG-level kernels (nhalf >= 512, l == 64).
// ===========================================================================
__device__ __forceinline__ void decomp_row(const float* __restrict__ src,
                                           const float* __restrict__ ec_s,
                                           const float* __restrict__ ec_d,
                                           float* d, float* s)
{
  float xa[32];
#pragma unroll
  for (int q = 0; q < 8; ++q) {
    float4 v = reinterpret_cast<const float4*>(src)[q];
    xa[q*4+0] = v.x; xa[q*4+1] = v.y; xa[q*4+2] = v.z; xa[q*4+3] = v.w;
  }
#pragma unroll
  for (int c = 0; c < 4; ++c) {
#pragma unroll
    for (int j = 0; j < 4; ++j) {
      float ad = 0.f, as = 0.f;
#pragma unroll
      for (int m = 0; m < 4; ++m) {
        const float xe = xa[c*4+m];
        const float xo = xa[16+c*4+m];
        ad += xe * ec_d[m*4+j] + xo * ec_d[(4+m)*4+j];
        as += xe * ec_s[m*4+j] + xo * ec_s[(4+m)*4+j];
      }
      d[c*4+j] = ad; s[c*4+j] = as;
    }
  }
}

// Fused decomposition + paired truncated forward DFT (radix-2 on time axis).
// grid (B, nhalf/512), block 256. nhalf >= 512.
__global__ __launch_bounds__(256) void fwd_big(
    const float* __restrict__ xin, float* __restrict__ xout,
    float* __restrict__ Fd, float* __restrict__ Fx,
    const float* __restrict__ ec_s, const float* __restrict__ ec_d,
    int nhalf)
{
  __shared__ float smem[16384];              // Pd,Md,Ps,Ms [256][16]
  float* Pd = smem;
  float* Md = smem + 4096;
  float* Ps = smem + 8192;
  float* Ms = smem + 12288;
  const int b    = blockIdx.x;
  const int t0p  = blockIdx.y << 8;
  const int tid  = threadIdx.x;
  const int halfn = nhalf >> 1;
  const int p    = t0p + tid;                // pair index < halfn

  float da[16], sa[16], db[16], sb[16];
  const size_t rowbase = (size_t)b * (2 * (size_t)nhalf) * CKd;
  decomp_row(xin + rowbase + (2*(size_t)p)*CKd,           ec_s, ec_d, da, sa);
  decomp_row(xin + rowbase + (2*(size_t)(p+halfn))*CKd,   ec_s, ec_d, db, sb);
  {
    float4* o0 = reinterpret_cast<float4*>(xout + ((size_t)b*nhalf + p)*CKd);
    float4* o1 = reinterpret_cast<float4*>(xout + ((size_t)b*nhalf + p + halfn)*CKd);
#pragma unroll
    for (int q = 0; q < 4; ++q) {
      o0[q] = make_float4(sa[q*4], sa[q*4+1], sa[q*4+2], sa[q*4+3]);
      o1[q] = make_float4(sb[q*4], sb[q*4+1], sb[q*4+2], sb[q*4+3]);
    }
  }
#pragma unroll
  for (int i = 0; i < 16; ++i) {
    Pd[tid*16+i] = da[i] + db[i];
    Md[tid*16+i] = da[i] - db[i];
    Ps[tid*16+i] = sa[i] + sb[i];
    Ms[tid*16+i] = sa[i] - sb[i];
  }
  __syncthreads();

  const int f = tid >> 2, g = tid & 3;       // f in [0,64)
  const float* srcd = (f & 1) ? Md : Pd;
  const float* srcs = (f & 1) ? Ms : Ps;
  const int   mask = nhalf - 1;
  const float w    = TWO_PI / (float)nhalf;
  float cv, sv, c1, s1;
  __sincosf((float)((f * t0p) & mask) * w, &sv, &cv);   // theta at p = t0p
  __sincosf((float)f * w, &s1, &c1);                    // step f*w
  float dre[4] = {0,0,0,0}, dim_[4] = {0,0,0,0};
  float sre[4] = {0,0,0,0}, sim_[4] = {0,0,0,0};
  for (int tt = 0; tt < 256; ++tt) {
    const float4 dv = *reinterpret_cast<const float4*>(srcd + tt*16 + g*4);
    const float4 xv = *reinterpret_cast<const float4*>(srcs + tt*16 + g*4);
    dre[0] += dv.x*cv; dim_[0] -= dv.x*sv;
    dre[1] += dv.y*cv; dim_[1] -= dv.y*sv;
    dre[2] += dv.z*cv; dim_[2] -= dv.z*sv;
    dre[3] += dv.w*cv; dim_[3] -= dv.w*sv;
    sre[0] += xv.x*cv; sim_[0] -= xv.x*sv;
    sre[1] += xv.y*cv; sim_[1] -= xv.y*sv;
    sre[2] += xv.z*cv; sim_[2] -= xv.z*sv;
    sre[3] += xv.w*cv; sim_[3] -= xv.w*sv;
    const float nc = cv*c1 - sv*s1;
    const float ns = sv*c1 + cv*s1;
    cv = nc; sv = ns;
  }
#pragma unroll
  for (int q = 0; q < 4; ++q) {
    const int i = g*4 + q;
    const int base = ((b * CKd + i) * 64 + f) * 2;
    atomicAdd(&Fd[base],   dre[q]);
    atomicAdd(&Fd[base+1], dim_[q]);
    atomicAdd(&Fx[base],   sre[q]);
    atomicAdd(&Fx[base+1], sim_[q]);
  }
}

// ---------------------------------------------------------------------------
// mix2: coalesced channel mixing for ALL levels. One block per batch element.
// thread = (o = tid>>4, fs = tid&15) handling f = 4*fs .. 4*fs+3 via float4.
// Writes packed G4 (b,o,f,4) = (udRe,udIm,usRe,usIm); zeros Fd/Fx after use.
// grid (BB), block 256.
// ---------------------------------------------------------------------------
__global__ __launch_bounds__(256) void mix2_kernel(
    float* __restrict__ Fd, float* __restrict__ Fx,
    float* __restrict__ G4,
    const float* __restrict__ wAre, const float* __restrict__ wAim,
    const float* __restrict__ wBre, const float* __restrict__ wBim,
    const float* __restrict__ wCre, const float* __restrict__ wCim)
{
  const int b  = blockIdx.x;
  const int tid = threadIdx.x;
  const int o  = tid >> 4;
  const int fs = tid & 15;

  const float4* Fd4 = reinterpret_cast<const float4*>(Fd);
  const float4* Fx4 = reinterpret_cast<const float4*>(Fx);

  float udre[4] = {0,0,0,0}, udim[4] = {0,0,0,0};
  float usre[4] = {0,0,0,0}, usim[4] = {0,0,0,0};

#pragma unroll 2
  for (int i = 0; i < 16; ++i) {
    const int wb4 = (i*16 + o)*16 + fs;            // float4 index into weights
    const float4 war = reinterpret_cast<const float4*>(wAre)[wb4];
    const float4 wai = reinterpret_cast<const float4*>(wAim)[wb4];
    const float4 wbr = reinterpret_cast<const float4*>(wBre)[wb4];
    const float4 wbi = reinterpret_cast<const float4*>(wBim)[wb4];
    const float4 wcr = reinterpret_cast<const float4*>(wCre)[wb4];
    const float4 wci = reinterpret_cast<const float4*>(wCim)[wb4];
    const int fb4 = (b*16 + i)*32 + 2*fs;          // float4 index into Fd/Fx
    const float4 d01 = Fd4[fb4], d23 = Fd4[fb4+1];
    const float4 x01 = Fx4[fb4], x23 = Fx4[fb4+1];

    const float fdre[4] = {d01.x, d01.z, d23.x, d23.z};
    const float fdim[4] = {d01.y, d01.w, d23.y, d23.w};
    const float fxre[4] = {x01.x, x01.z, x23.x, x23.z};
    const float fxim[4] = {x01.y, x01.w, x23.y, x23.w};
    const float ware[4] = {war.x, war.y, war.z, war.w};
    const float waim[4] = {wai.x, wai.y, wai.z, wai.w};
    const float wbre[4] = {wbr.x, wbr.y, wbr.z, wbr.w};
    const float wbim[4] = {wbi.x, wbi.y, wbi.z, wbi.w};
    const float wcre[4] = {wcr.x, wcr.y, wcr.z, wcr.w};
    const float wcim[4] = {wci.x, wci.y, wci.z, wci.w};
#pragma unroll
    for (int j = 0; j < 4; ++j) {
      udre[j] += fdre[j]*ware[j] - fdim[j]*waim[j] + fxre[j]*wbre[j] - fxim[j]*wbim[j];
      udim[j] += fdre[j]*waim[j] + fdim[j]*ware[j] + fxre[j]*wbim[j] + fxim[j]*wbre[j];
      usre[j] += fdre[j]*wcre[j] - fdim[j]*wcim[j];
      usim[j] += fdre[j]*wcim[j] + fdim[j]*wcre[j];
    }
  }
  float4* G4f = reinterpret_cast<float4*>(G4);
#pragma unroll
  for (int j = 0; j < 4; ++j)
    G4f[(b*16 + o)*64 + 4*fs + j] = make_float4(udre[j], udim[j], usre[j], usim[j]);

  __syncthreads();   // all reads of this b's Fd/Fx slice done -> safe to zero
  {
    float4* Fdw = reinterpret_cast<float4*>(Fd);
    float4* Fxw = reinterpret_cast<float4*>(Fx);
    const int fb4 = (b*16 + o)*32 + 2*fs;
    const float4 z = make_float4(0.f, 0.f, 0.f, 0.f);
    Fdw[fb4] = z; Fdw[fb4+1] = z;
    Fxw[fb4] = z; Fxw[fb4+1] = z;
  }
}

// Channel-per-lane inverse truncated rfft (l=64, no Nyquist), E/O radix-2
// output symmetry, 8 t-pairs per thread, one-deep register prefetch of G.
// grid (B, n/256), block 256.
__global__ __launch_bounds__(256) void inv_big(
    const float* __restrict__ G4, float* __restrict__ Ud, float* __restrict__ Us,
    int n)
{
  __shared__ float4 gl[64 * 17];             // [f][i] padded: idx = f*17+i
  const int b   = blockIdx.x;
  const int tid = threadIdx.x;
  const float4* Gb = reinterpret_cast<const float4*>(G4) + (size_t)b * 1024;
  for (int s_ = tid; s_ < 1024; s_ += 256) {
    const int i = s_ >> 6, f = s_ & 63;      // coalesced global read
    float4 v = Gb[(size_t)i * 64 + f];
    if (f) { v.x *= 2.f; v.y *= 2.f; v.z *= 2.f; v.w *= 2.f; }   // mode weight
    gl[f*17 + i] = v;
  }
  __syncthreads();

  const int i    = tid & 15;                 // channel
  const int col  = tid >> 4;                 // 0..15
  const int base = blockIdx.y << 7;          // 128 pairs per block
  const float w  = TWO_PI / (float)n;

  float udE[8], udO[8], usE[8], usO[8], c[8], s[8], c1[8], s1[8];
  {
    const float4 g0 = gl[i];                 // f = 0 (DC, weight 1)
#pragma unroll
    for (int k = 0; k < 8; ++k) {
      udE[k] = g0.x; usE[k] = g0.z; udO[k] = 0.f; usO[k] = 0.f;
      __sincosf((float)(base + col + 16*k) * w, &s1[k], &c1[k]);
      c[k] = c1[k]; s[k] = s1[k];            // f = 1
    }
  }
  float4 ga = gl[17 + i];                    // prefetch f = 1
#pragma unroll 1
  for (int kk = 0; kk < 31; ++kk) {
    const float4 gb = gl[(2*kk+2)*17 + i];   // prefetch even while using odd
#pragma unroll
    for (int k = 0; k < 8; ++k) {            // f = 2kk+1 (odd)
      udO[k] += ga.x*c[k] - ga.y*s[k];
      usO[k] += ga.z*c[k] - ga.w*s[k];
      const float nc = c[k]*c1[k] - s[k]*s1[k];
      const float ns = s[k]*c1[k] + c[k]*s1[k];
      c[k] = nc; s[k] = ns;
    }
    const float4 gn = gl[(2*kk+3)*17 + i];   // prefetch next odd
#pragma unroll
    for (int k = 0; k < 8; ++k) {            // f = 2kk+2 (even)
      udE[k] += gb.x*c[k] - gb.y*s[k];
      usE[k] += gb.z*c[k] - gb.w*s[k];
      const float nc = c[k]*c1[k] - s[k]*s1[k];
      const float ns = s[k]*c1[k] + c[k]*s1[k];
      c[k] = nc; s[k] = ns;
    }
    ga = gn;
  }
#pragma unroll
  for (int k = 0; k < 8; ++k) {              // f = 63 (odd), prefetched in ga
    udO[k] += ga.x*c[k] - ga.y*s[k];
    usO[k] += ga.z*c[k] - ga.w*s[k];
  }
  const float invn = 1.f / (float)n;
  const int   half = n >> 1;
#pragma unroll
  for (int k = 0; k < 8; ++k) {
    const int t = base + col + 16*k;
    const size_t r0 = ((size_t)b*n + t) * CKd + i;
    const size_t r1 = r0 + (size_t)half * CKd;
    Ud[r0] = (udE[k] + udO[k]) * invn;
    Ud[r1] = (udE[k] - udO[k]) * invn;
    Us[r0] = (usE[k] + usO[k]) * invn;
    Us[r1] = (usE[k] - usO[k]) * invn;
  }
}

// ===========================================================================
// Small-level kernels + recon/t0.
// ===========================================================================
__global__ __launch_bounds__(256) void fwd_kernel(
    const float* __restrict__ xin, float* __restrict__ xout,
    float* __restrict__ Fd, float* __restrict__ Fx,
    const float* __restrict__ ec_s, const float* __restrict__ ec_d,
    int nhalf, int l)
{
  __shared__ float dt[256][20];
  __shared__ float st[256][20];
  const int b   = blockIdx.x;
  const int t0  = blockIdx.y << 8;
  const int tid = threadIdx.x;
  const int rem = nhalf - t0;
  const int rows = rem < 256 ? rem : 256;
  const int t = t0 + tid;

  if (tid < rows) {
    const float* src = xin + ((size_t)b * (2 * (size_t)nhalf) + 2 * (size_t)t) * CKd;
    float xa[32];
#pragma unroll
    for (int q = 0; q < 8; ++q) {
      float4 v = reinterpret_cast<const float4*>(src)[q];
      xa[q*4+0] = v.x; xa[q*4+1] = v.y; xa[q*4+2] = v.z; xa[q*4+3] = v.w;
    }
    float srow[16];
#pragma unroll
    for (int c = 0; c < 4; ++c) {
#pragma unroll
      for (int j = 0; j < 4; ++j) {
        float ad = 0.f, as = 0.f;
#pragma unroll
        for (int m = 0; m < 4; ++m) {
          const float xe = xa[c*4+m];
          const float xo = xa[16+c*4+m];
          ad += xe * ec_d[m*4+j] + xo * ec_d[(4+m)*4+j];
          as += xe * ec_s[m*4+j] + xo * ec_s[(4+m)*4+j];
        }
        dt[tid][c*4+j] = ad;
        st[tid][c*4+j] = as;
        srow[c*4+j]    = as;
      }
    }
    float4* dst = reinterpret_cast<float4*>(xout + ((size_t)b * nhalf + t) * CKd);
#pragma unroll
    for (int q = 0; q < 4; ++q)
      dst[q] = make_float4(srow[q*4], srow[q*4+1], srow[q*4+2], srow[q*4+3]);
  }
  __syncthreads();

  const int f = tid >> 2, g = tid & 3;
  if (f >= l) return;
  float dre[4] = {0,0,0,0}, dim_[4] = {0,0,0,0};
  float sre[4] = {0,0,0,0}, sim_[4] = {0,0,0,0};
  const int   mask = nhalf - 1;
  const float w    = TWO_PI / (float)nhalf;
  for (int tt = 0; tt < rows; ++tt) {
    const int tg = t0 + tt;
    float sv, cv;
    __sincosf((float)((f * tg) & mask) * w, &sv, &cv);
    const float4 dv = *reinterpret_cast<const float4*>(&dt[tt][g*4]);
    const float4 xv = *reinterpret_cast<const float4*>(&st[tt][g*4]);
    const float dvv[4] = {dv.x, dv.y, dv.z, dv.w};
    const float xvv[4] = {xv.x, xv.y, xv.z, xv.w};
#pragma unroll
    for (int q = 0; q < 4; ++q) {
      dre[q] += dvv[q] * cv;  dim_[q] -= dvv[q] * sv;
      sre[q] += xvv[q] * cv;  sim_[q] -= xvv[q] * sv;
    }
  }
#pragma unroll
  for (int q = 0; q < 4; ++q) {
    const int i = g*4 + q;
    const int base = ((b * CKd + i) * 64 + f) * 2;
    atomicAdd(&Fd[base],   dre[q]);
    atomicAdd(&Fd[base+1], dim_[q]);
    atomicAdd(&Fx[base],   sre[q]);
    atomicAdd(&Fx[base+1], sim_[q]);
  }
}

__global__ __launch_bounds__(256) void inv_kernel(
    const float* __restrict__ G4,
    float* __restrict__ Ud, float* __restrict__ Us, int n, int l)
{
  __shared__ float4 sG[64 * 16];
  const int b = blockIdx.x;
  const int tid = threadIdx.x;
  const float4* Gb = reinterpret_cast<const float4*>(G4) + (size_t)b * 1024;
  for (int s_ = tid; s_ < 1024; s_ += 256) {
    const int i = s_ >> 6, f = s_ & 63;      // coalesced
    if (f < l) sG[f*16 + i] = Gb[(size_t)i * 64 + f];
  }
  __syncthreads();
  const int t = (blockIdx.y << 8) + tid;
  if (t >= n) return;

  float ud[16], us[16];
#pragma unroll
  for (int i = 0; i < 16; ++i) { const float4 g = sG[i]; ud[i] = g.x; us[i] = g.z; }

  const int   mask = n - 1;
  const float w    = TWO_PI / (float)n;
  for (int f = 1; f < l; ++f) {
    float sv, cv;
    __sincosf((float)((f * t) & mask) * w, &sv, &cv);
    const float scale = (2 * f == n) ? 1.f : 2.f;
    cv *= scale; sv *= scale;
#pragma unroll
    for (int i = 0; i < 16; ++i) {
      const float4 g = sG[f * 16 + i];
      ud[i] += g.x * cv - g.y * sv;
      us[i] += g.z * cv - g.w * sv;
    }
  }
  const float invn = 1.f / (float)n;
  const size_t ro = ((size_t)b * n + t) * CKd;
  float4* pud = reinterpret_cast<float4*>(Ud + ro);
  float4* pus = reinterpret_cast<float4*>(Us + ro);
#pragma unroll
  for (int q = 0; q < 4; ++q) {
    pud[q] = make_float4(ud[q*4]*invn, ud[q*4+1]*invn, ud[q*4+2]*invn, ud[q*4+3]*invn);
    pus[q] = make_float4(us[q*4]*invn, us[q*4+1]*invn, us[q*4+2]*invn, us[q*4+3]*invn);
  }
}

__global__ void t0_kernel(const float* __restrict__ xin, float* __restrict__ xout,
                          const float* __restrict__ t0w, const float* __restrict__ t0b)
{
  const int idx = blockIdx.x * 256 + threadIdx.x;
  if (idx >= BB * CKd) return;
  const int bc = idx >> 2;
  const int k  = idx & 3;
  float acc = t0b[k];
#pragma unroll
  for (int j = 0; j < 4; ++j) acc += xin[bc*4 + j] * t0w[k*4 + j];
  xout[idx] = acc;
}

__global__ __launch_bounds__(256) void recon_kernel(
    const float* __restrict__ xin, const float* __restrict__ UsL,
    const float* __restrict__ UdL, float* __restrict__ xout,
    int n, int lg, const float* __restrict__ rc_e, const float* __restrict__ rc_o)
{
  const int idx = blockIdx.x * 256 + threadIdx.x;
  if (idx >= BB * n) return;
  const int b = idx >> lg;
  const int t = idx & (n - 1);
  const size_t ro = ((size_t)b * n + t) * CKd;
  float xv[16], uv[16], dv[16];
#pragma unroll
  for (int q = 0; q < 4; ++q) {
    const float4 a = reinterpret_cast<const float4*>(xin + ro)[q];
    const float4 u = reinterpret_cast<const float4*>(UsL + ro)[q];
    const float4 d = reinterpret_cast<const float4*>(UdL + ro)[q];
    xv[q*4]=a.x; xv[q*4+1]=a.y; xv[q*4+2]=a.z; xv[q*4+3]=a.w;
    uv[q*4]=u.x; uv[q*4+1]=u.y; uv[q*4+2]=u.z; uv[q*4+3]=u.w;
    dv[q*4]=d.x; dv[q*4+1]=d.y; dv[q*4+2]=d.z; dv[q*4+3]=d.w;
  }
  float xe[16], xo[16];
#pragma unroll
  for (int c = 0; c < 4; ++c) {
    float xc[8];
#pragma unroll
    for (int m = 0; m < 4; ++m) { xc[m] = xv[c*4+m] + uv[c*4+m]; xc[4+m] = dv[c*4+m]; }
#pragma unroll
    for (int k = 0; k < 4; ++k) {
      float ae = 0.f, ao = 0.f;
#pragma unroll
      for (int m = 0; m < 8; ++m) { ae += xc[m] * rc_e[m*4+k]; ao += xc[m] * rc_o[m*4+k]; }
      xe[c*4+k] = ae; xo[c*4+k] = ao;
    }
  }
  float4* out = reinterpret_cast<float4*>(xout + ((size_t)b * (2*(size_t)n) + 2*(size_t)t) * CKd);
#pragma unroll
  for (int q = 0; q < 4; ++q) {
    out[q]   = make_float4(xe[q*4], xe[q*4+1], xe[q*4+2], xe[q*4+3]);
    out[4+q] = make_float4(xo[q*4], xo[q*4+1], xo[q*4+2], xo[q*4+3]);
  }
}

// ---------------------------------------------------------------------------
extern "C" void kernel_launch(void* const* d_in, const int* in_sizes, int n_in,
                              void* d_out, int out_size, void* d_ws, size_t ws_size,
                              hipStream_t stream)
{
  const float* x    = (const float*)d_in[0];
  const float* ec_s = (const float*)d_in[1];
  const float* ec_d = (const float*)d_in[2];
  const float* rc_e = (const float*)d_in[3];
  const float* rc_o = (const float*)d_in[4];
  const float* t0w  = (const float*)d_in[5];
  const float* t0b  = (const float*)d_in[6];
  const float* wAre = (const float*)d_in[7];
  const float* wAim = (const float*)d_in[8];
  const float* wBre = (const float*)d_in[9];
  const float* wBim = (const float*)d_in[10];
  const float* wCre = (const float*)d_in[11];
  const float* wCim = (const float*)d_in[12];

  float* ws = (float*)d_ws;
  const size_t XS_ELEMS = (size_t)BB * (NTOT/2) * CKd;   // 4,194,304
  const size_t U_ELEMS  = (size_t)BB * (NTOT - 1) * CKd; // 8,388,096
  const size_t F_ELEMS  = (size_t)BB * CKd * 64 * 2;     // 65,536
  float* xsA = ws;
  float* xsB = xsA + XS_ELEMS;
  float* UdS = xsB + XS_ELEMS;
  float* UsS = UdS + U_ELEMS;
  float* Fd  = UsS + U_ELEMS;
  float* Fx  = Fd + F_ELEMS;
  float* G4  = Fx + F_ELEMS;                             // 2*F_ELEMS floats

  float* udl[NLEV]; float* usl[NLEV]; int nlv[NLEV];

  // single upfront zero of the atomic targets; mix2 re-zeros per level
  hipMemsetAsync(Fd, 0, 2 * F_ELEMS * sizeof(float), stream);

  // ---- decomposition ----
  const float* cur = x;
  float* nxt = xsA;
  size_t uoff = 0;
  int nhalf = NTOT / 2;
  for (int j = 0; j < NLEV; ++j, nhalf >>= 1) {
    const int l = (nhalf/2 + 1 < 64) ? (nhalf/2 + 1) : 64;
    udl[j] = UdS + uoff; usl[j] = UsS + uoff; nlv[j] = nhalf;
    if (nhalf >= 512) {
      fwd_big<<<dim3(BB, nhalf/512), 256, 0, stream>>>(cur, nxt, Fd, Fx, ec_s, ec_d, nhalf);
      mix2_kernel<<<BB, 256, 0, stream>>>(Fd, Fx, G4,
                                          wAre, wAim, wBre, wBim, wCre, wCim);
      inv_big<<<dim3(BB, nhalf/256), 256, 0, stream>>>(G4, udl[j], usl[j], nhalf);
    } else {
      fwd_kernel<<<dim3(BB, 1), 256, 0, stream>>>(cur, nxt, Fd, Fx, ec_s, ec_d, nhalf, l);
      mix2_kernel<<<BB, 256, 0, stream>>>(Fd, Fx, G4,
                                          wAre, wAim, wBre, wBim, wCre, wCim);
      inv_kernel<<<dim3(BB, 1), 256, 0, stream>>>(G4, udl[j], usl[j], nhalf, l);
    }
    uoff += (size_t)BB * nhalf * CKd;
    cur = nxt;
    nxt = (nxt == xsA) ? xsB : xsA;
  }

  // ---- coarsest-scale T0 ----
  t0_kernel<<<2, 256, 0, stream>>>(cur, nxt, t0w, t0b);
  cur = nxt;
  nxt = (nxt == xsA) ? xsB : xsA;

  // ---- reconstruction ----
  for (int i = NLEV - 1; i >= 0; --i) {
    const int n = nlv[i];
    int lg = 0; while ((1 << lg) < n) ++lg;
    float* out = (i == 0) ? (float*)d_out : nxt;
    const int total = BB * n;
    recon_kernel<<<(total + 255) / 256, 256, 0, stream>>>(cur, usl[i], udl[i], out,
                                                          n, lg, rc_e, rc_o);
    cur = out;
    nxt = (nxt == xsA) ? xsB : xsA;
  }
}

// Round 8
// 618.037 us; speedup vs baseline: 1.1530x; 1.1530x over previous
//
#include <hip/hip_runtime.h>

#define TWO_PI 6.28318530717958647692f

constexpr int BB   = 32;     // batch
constexpr int NTOT = 16384;  // sequence length
constexpr int CKd  = 16;     // C*K channels
constexpr int NLEV = 14;     // log2(NTOT)

__device__ __forceinline__ void decomp_row(const float* __restrict__ src,
                                           const float* __restrict__ ec_s,
                                           const float* __restrict__ ec_d,
                                           float* d, float* s)
{
  float xa[32];
#pragma unroll
  for (int q = 0; q < 8; ++q) {
    float4 v = reinterpret_cast<const float4*>(src)[q];
    xa[q*4+0] = v.x; xa[q*4+1] = v.y; xa[q*4+2] = v.z; xa[q*4+3] = v.w;
  }
#pragma unroll
  for (int c = 0; c < 4; ++c) {
#pragma unroll
    for (int j = 0; j < 4; ++j) {
      float ad = 0.f, as = 0.f;
#pragma unroll
      for (int m = 0; m < 4; ++m) {
        const float xe = xa[c*4+m];
        const float xo = xa[16+c*4+m];
        ad += xe * ec_d[m*4+j] + xo * ec_d[(4+m)*4+j];
        as += xe * ec_s[m*4+j] + xo * ec_s[(4+m)*4+j];
      }
      d[c*4+j] = ad; s[c*4+j] = as;
    }
  }
}

// ===========================================================================
// fwd_big v2 (nhalf >= 512): 128 pairs/block, [128][20] LDS (40KB, 4 blk/CU),
// all-256-thread decomp + in-place butterfly, wave=channel-group DFT with
// uniform-broadcast LDS reads. grid (B, nhalf/256), block 256.
// ===========================================================================
__global__ __launch_bounds__(256) void fwd_big(
    const float* __restrict__ xin, float* __restrict__ xout,
    float* __restrict__ Fd, float* __restrict__ Fx,
    const float* __restrict__ ec_s, const float* __restrict__ ec_d,
    int nhalf)
{
  __shared__ float smem[4 * 128 * 20];       // Pd,Md,Ps,Ms [128][20]
  float* Pd = smem;
  float* Md = smem + 2560;
  float* Ps = smem + 5120;
  float* Ms = smem + 7680;
  const int b    = blockIdx.x;
  const int p0   = blockIdx.y << 7;          // pair base (128 pairs/block)
  const int tid  = threadIdx.x;
  const int halfn = nhalf >> 1;

  // ---- phase 1a: decomp, one row per thread (h=0: row p; h=1: row p+halfn)
  {
    const int h = tid >> 7, r = tid & 127;
    const int t = p0 + r + h * halfn;
    float d[16], s[16];
    const size_t rowbase = (size_t)b * (2 * (size_t)nhalf) * CKd;
    decomp_row(xin + rowbase + (2*(size_t)t)*CKd, ec_s, ec_d, d, s);
    float4* o0 = reinterpret_cast<float4*>(xout + ((size_t)b*nhalf + t)*CKd);
    float* dd = (h ? Md : Pd) + r*20;
    float* ds = (h ? Ms : Ps) + r*20;
#pragma unroll
    for (int q = 0; q < 4; ++q) {
      o0[q] = make_float4(s[q*4], s[q*4+1], s[q*4+2], s[q*4+3]);
      *reinterpret_cast<float4*>(dd + q*4) = make_float4(d[q*4], d[q*4+1], d[q*4+2], d[q*4+3]);
      *reinterpret_cast<float4*>(ds + q*4) = make_float4(s[q*4], s[q*4+1], s[q*4+2], s[q*4+3]);
    }
  }
  __syncthreads();
  // ---- phase 1b: in-place butterfly a,b -> a+b, a-b
#pragma unroll
  for (int k = 0; k < 8; ++k) {
    const int v = tid + (k << 8);            // 0..2047 valid elements
    const int off = (v >> 4) * 20 + (v & 15);
    const float a  = Pd[off], bb = Md[off];
    Pd[off] = a + bb;  Md[off] = a - bb;
    const float as = Ps[off], bs = Ms[off];
    Ps[off] = as + bs; Ms[off] = as - bs;
  }
  __syncthreads();

  // ---- phase 2: DFT. wave g = tid>>6 (channel group), lane f = tid&63.
  const int g = tid >> 6, f = tid & 63;
  const float* srcd = (f & 1) ? Md : Pd;
  const float* srcs = (f & 1) ? Ms : Ps;
  const int   mask = nhalf - 1;
  const float w    = TWO_PI / (float)nhalf;
  float cv, sv, c1, s1;
  __sincosf((float)((f * p0) & mask) * w, &sv, &cv);   // theta at p = p0
  __sincosf((float)f * w, &s1, &c1);                   // step f*w
  float dre[4] = {0,0,0,0}, dim_[4] = {0,0,0,0};
  float sre[4] = {0,0,0,0}, sim_[4] = {0,0,0,0};
  for (int tt = 0; tt < 128; ++tt) {
    const float4 dv = *reinterpret_cast<const float4*>(srcd + tt*20 + g*4);
    const float4 xv = *reinterpret_cast<const float4*>(srcs + tt*20 + g*4);
    dre[0] += dv.x*cv; dim_[0] -= dv.x*sv;
    dre[1] += dv.y*cv; dim_[1] -= dv.y*sv;
    dre[2] += dv.z*cv; dim_[2] -= dv.z*sv;
    dre[3] += dv.w*cv; dim_[3] -= dv.w*sv;
    sre[0] += xv.x*cv; sim_[0] -= xv.x*sv;
    sre[1] += xv.y*cv; sim_[1] -= xv.y*sv;
    sre[2] += xv.z*cv; sim_[2] -= xv.z*sv;
    sre[3] += xv.w*cv; sim_[3] -= xv.w*sv;
    const float nc = cv*c1 - sv*s1;
    const float ns = sv*c1 + cv*s1;
    cv = nc; sv = ns;
  }
#pragma unroll
  for (int q = 0; q < 4; ++q) {
    const int i = g*4 + q;
    const int base = ((b * CKd + i) * 64 + f) * 2;
    atomicAdd(&Fd[base],   dre[q]);
    atomicAdd(&Fd[base+1], dim_[q]);
    atomicAdd(&Fx[base],   sre[q]);
    atomicAdd(&Fx[base+1], sim_[q]);
  }
}

// ---------------------------------------------------------------------------
// mix2 (big levels): coalesced channel mixing, one block per batch element.
// Writes packed G4 (b,o,f,4); zeros Fd/Fx after use. grid (BB), block 256.
// ---------------------------------------------------------------------------
__global__ __launch_bounds__(256) void mix2_kernel(
    float* __restrict__ Fd, float* __restrict__ Fx,
    float* __restrict__ G4,
    const float* __restrict__ wAre, const float* __restrict__ wAim,
    const float* __restrict__ wBre, const float* __restrict__ wBim,
    const float* __restrict__ wCre, const float* __restrict__ wCim)
{
  const int b  = blockIdx.x;
  const int tid = threadIdx.x;
  const int o  = tid >> 4;
  const int fs = tid & 15;

  const float4* Fd4 = reinterpret_cast<const float4*>(Fd);
  const float4* Fx4 = reinterpret_cast<const float4*>(Fx);

  float udre[4] = {0,0,0,0}, udim[4] = {0,0,0,0};
  float usre[4] = {0,0,0,0}, usim[4] = {0,0,0,0};

#pragma unroll 2
  for (int i = 0; i < 16; ++i) {
    const int wb4 = (i*16 + o)*16 + fs;
    const float4 war = reinterpret_cast<const float4*>(wAre)[wb4];
    const float4 wai = reinterpret_cast<const float4*>(wAim)[wb4];
    const float4 wbr = reinterpret_cast<const float4*>(wBre)[wb4];
    const float4 wbi = reinterpret_cast<const float4*>(wBim)[wb4];
    const float4 wcr = reinterpret_cast<const float4*>(wCre)[wb4];
    const float4 wci = reinterpret_cast<const float4*>(wCim)[wb4];
    const int fb4 = (b*16 + i)*32 + 2*fs;
    const float4 d01 = Fd4[fb4], d23 = Fd4[fb4+1];
    const float4 x01 = Fx4[fb4], x23 = Fx4[fb4+1];

    const float fdre[4] = {d01.x, d01.z, d23.x, d23.z};
    const float fdim[4] = {d01.y, d01.w, d23.y, d23.w};
    const float fxre[4] = {x01.x, x01.z, x23.x, x23.z};
    const float fxim[4] = {x01.y, x01.w, x23.y, x23.w};
    const float ware[4] = {war.x, war.y, war.z, war.w};
    const float waim[4] = {wai.x, wai.y, wai.z, wai.w};
    const float wbre[4] = {wbr.x, wbr.y, wbr.z, wbr.w};
    const float wbim[4] = {wbi.x, wbi.y, wbi.z, wbi.w};
    const float wcre[4] = {wcr.x, wcr.y, wcr.z, wcr.w};
    const float wcim[4] = {wci.x, wci.y, wci.z, wci.w};
#pragma unroll
    for (int j = 0; j < 4; ++j) {
      udre[j] += fdre[j]*ware[j] - fdim[j]*waim[j] + fxre[j]*wbre[j] - fxim[j]*wbim[j];
      udim[j] += fdre[j]*waim[j] + fdim[j]*ware[j] + fxre[j]*wbim[j] + fxim[j]*wbre[j];
      usre[j] += fdre[j]*wcre[j] - fdim[j]*wcim[j];
      usim[j] += fdre[j]*wcim[j] + fdim[j]*wcre[j];
    }
  }
  float4* G4f = reinterpret_cast<float4*>(G4);
#pragma unroll
  for (int j = 0; j < 4; ++j)
    G4f[(b*16 + o)*64 + 4*fs + j] = make_float4(udre[j], udim[j], usre[j], usim[j]);

  __syncthreads();
  {
    float4* Fdw = reinterpret_cast<float4*>(Fd);
    float4* Fxw = reinterpret_cast<float4*>(Fx);
    const int fb4 = (b*16 + o)*32 + 2*fs;
    const float4 z = make_float4(0.f, 0.f, 0.f, 0.f);
    Fdw[fb4] = z; Fdw[fb4+1] = z;
    Fxw[fb4] = z; Fxw[fb4+1] = z;
  }
}

// ---------------------------------------------------------------------------
// inv_big: channel-per-lane inverse truncated rfft (l=64), E/O radix-2 output
// symmetry, 8 t-pairs/thread, register prefetch. grid (B, n/256), block 256.
// ---------------------------------------------------------------------------
__global__ __launch_bounds__(256) void inv_big(
    const float* __restrict__ G4, float* __restrict__ Ud, float* __restrict__ Us,
    int n)
{
  __shared__ float4 gl[64 * 17];
  const int b   = blockIdx.x;
  const int tid = threadIdx.x;
  const float4* Gb = reinterpret_cast<const float4*>(G4) + (size_t)b * 1024;
  for (int s_ = tid; s_ < 1024; s_ += 256) {
    const int i = s_ >> 6, f = s_ & 63;
    float4 v = Gb[(size_t)i * 64 + f];
    if (f) { v.x *= 2.f; v.y *= 2.f; v.z *= 2.f; v.w *= 2.f; }
    gl[f*17 + i] = v;
  }
  __syncthreads();

  const int i    = tid & 15;
  const int col  = tid >> 4;
  const int base = blockIdx.y << 7;
  const float w  = TWO_PI / (float)n;

  float udE[8], udO[8], usE[8], usO[8], c[8], s[8], c1[8], s1[8];
  {
    const float4 g0 = gl[i];
#pragma unroll
    for (int k = 0; k < 8; ++k) {
      udE[k] = g0.x; usE[k] = g0.z; udO[k] = 0.f; usO[k] = 0.f;
      __sincosf((float)(base + col + 16*k) * w, &s1[k], &c1[k]);
      c[k] = c1[k]; s[k] = s1[k];
    }
  }
  float4 ga = gl[17 + i];
#pragma unroll 1
  for (int kk = 0; kk < 31; ++kk) {
    const float4 gb = gl[(2*kk+2)*17 + i];
#pragma unroll
    for (int k = 0; k < 8; ++k) {
      udO[k] += ga.x*c[k] - ga.y*s[k];
      usO[k] += ga.z*c[k] - ga.w*s[k];
      const float nc = c[k]*c1[k] - s[k]*s1[k];
      const float ns = s[k]*c1[k] + c[k]*s1[k];
      c[k] = nc; s[k] = ns;
    }
    const float4 gn = gl[(2*kk+3)*17 + i];
#pragma unroll
    for (int k = 0; k < 8; ++k) {
      udE[k] += gb.x*c[k] - gb.y*s[k];
      usE[k] += gb.z*c[k] - gb.w*s[k];
      const float nc = c[k]*c1[k] - s[k]*s1[k];
      const float ns = s[k]*c1[k] + c[k]*s1[k];
      c[k] = nc; s[k] = ns;
    }
    ga = gn;
  }
#pragma unroll
  for (int k = 0; k < 8; ++k) {
    udO[k] += ga.x*c[k] - ga.y*s[k];
    usO[k] += ga.z*c[k] - ga.w*s[k];
  }
  const float invn = 1.f / (float)n;
  const int   half = n >> 1;
#pragma unroll
  for (int k = 0; k < 8; ++k) {
    const int t = base + col + 16*k;
    const size_t r0 = ((size_t)b*n + t) * CKd + i;
    const size_t r1 = r0 + (size_t)half * CKd;
    Ud[r0] = (udE[k] + udO[k]) * invn;
    Ud[r1] = (udE[k] - udO[k]) * invn;
    Us[r0] = (usE[k] + usO[k]) * invn;
    Us[r1] = (usE[k] - usO[k]) * invn;
  }
}

// ===========================================================================
// small_level: fused decomp+DFT+mix+inv for one level with nh <= 256.
// One block per batch element; all intermediates in LDS; no atomics.
// grid (BB), block 256. LDS 58,368 B.
// ===========================================================================
__global__ __launch_bounds__(256) void small_level(
    const float* __restrict__ xin, float* __restrict__ xout,
    float* __restrict__ Ud, float* __restrict__ Us,
    const float* __restrict__ ec_s, const float* __restrict__ ec_d,
    const float* __restrict__ wAre, const float* __restrict__ wAim,
    const float* __restrict__ wBre, const float* __restrict__ wBim,
    const float* __restrict__ wCre, const float* __restrict__ wCim,
    int nh, int l)
{
  __shared__ float smem[14592];              // dL[256][20], sL[256][20], F4[64][17]f4
  float*  dL = smem;                         // 5120 floats
  float*  sL = smem + 5120;                  // 5120 floats
  float4* F4 = reinterpret_cast<float4*>(smem + 10240);  // [64][17] float4
  float4* GL = reinterpret_cast<float4*>(smem);          // aliases dL (dead by then)

  const int b = blockIdx.x, tid = threadIdx.x;

  // ---- phase A: decomposition ----
  if (tid < nh) {
    float d[16], s[16];
    decomp_row(xin + ((size_t)(b * 2 * nh + 2 * tid)) * CKd, ec_s, ec_d, d, s);
    float* dd = dL + tid*20;
    float* ds = sL + tid*20;
    float4* o0 = reinterpret_cast<float4*>(xout + ((size_t)(b*nh + tid))*CKd);
#pragma unroll
    for (int q = 0; q < 4; ++q) {
      *reinterpret_cast<float4*>(dd + q*4) = make_float4(d[q*4], d[q*4+1], d[q*4+2], d[q*4+3]);
      *reinterpret_cast<float4*>(ds + q*4) = make_float4(s[q*4], s[q*4+1], s[q*4+2], s[q*4+3]);
      o0[q] = make_float4(s[q*4], s[q*4+1], s[q*4+2], s[q*4+3]);
    }
  }
  __syncthreads();

  // ---- phase B: forward DFT (wave g = channel group, lane f = mode) ----
  {
    const int g = tid >> 6, f = tid & 63;
    if (f < l) {
      const float w = TWO_PI / (float)nh;
      float cv = 1.f, sv = 0.f, c1, s1;
      __sincosf((float)f * w, &s1, &c1);
      float dre[4] = {0,0,0,0}, dim_[4] = {0,0,0,0};
      float sre[4] = {0,0,0,0}, sim_[4] = {0,0,0,0};
      for (int tt = 0; tt < nh; ++tt) {
        const float4 dv = *reinterpret_cast<const float4*>(dL + tt*20 + g*4);
        const float4 xv = *reinterpret_cast<const float4*>(sL + tt*20 + g*4);
        dre[0] += dv.x*cv; dim_[0] -= dv.x*sv;
        dre[1] += dv.y*cv; dim_[1] -= dv.y*sv;
        dre[2] += dv.z*cv; dim_[2] -= dv.z*sv;
        dre[3] += dv.w*cv; dim_[3] -= dv.w*sv;
        sre[0] += xv.x*cv; sim_[0] -= xv.x*sv;
        sre[1] += xv.y*cv; sim_[1] -= xv.y*sv;
        sre[2] += xv.z*cv; sim_[2] -= xv.z*sv;
        sre[3] += xv.w*cv; sim_[3] -= xv.w*sv;
        const float nc = cv*c1 - sv*s1;
        const float ns = sv*c1 + cv*s1;
        cv = nc; sv = ns;
      }
#pragma unroll
      for (int q = 0; q < 4; ++q)
        F4[f*17 + g*4 + q] = make_float4(dre[q], dim_[q], sre[q], sim_[q]);
    }
  }
  __syncthreads();

  // ---- phase C: channel mixing (wave o2 = out-group, lane f = mode) ----
  {
    const int o2 = tid >> 6, f = tid & 63;
    if (f < l) {
      float udre[4] = {0,0,0,0}, udim[4] = {0,0,0,0};
      float usre[4] = {0,0,0,0}, usim[4] = {0,0,0,0};
#pragma unroll 4
      for (int i = 0; i < 16; ++i) {
        const float4 Fv = F4[f*17 + i];      // (dre, dim, sre, sim)
#pragma unroll
        for (int q = 0; q < 4; ++q) {
          const int o  = o2*4 + q;
          const int wb = (i * CKd + o) * 64 + f;
          const float war = wAre[wb], wai = wAim[wb];
          const float wbr = wBre[wb], wbi = wBim[wb];
          const float wcr = wCre[wb], wci = wCim[wb];
          udre[q] += Fv.x*war - Fv.y*wai + Fv.z*wbr - Fv.w*wbi;
          udim[q] += Fv.x*wai + Fv.y*war + Fv.z*wbi + Fv.w*wbr;
          usre[q] += Fv.x*wcr - Fv.y*wci;
          usim[q] += Fv.x*wci + Fv.y*wcr;
        }
      }
#pragma unroll
      for (int q = 0; q < 4; ++q)
        GL[f*17 + o2*4 + q] = make_float4(udre[q], udim[q], usre[q], usim[q]);
    }
  }
  __syncthreads();

  // ---- phase D: inverse truncated rfft ----
  if (tid < nh) {
    const int t = tid;
    const float w = TWO_PI / (float)nh;
    float ud[16], us[16];
#pragma unroll
    for (int i = 0; i < 16; ++i) { const float4 g = GL[i]; ud[i] = g.x; us[i] = g.z; }
    float c1, s1;
    __sincosf((float)t * w, &s1, &c1);
    float cv = c1, sv = s1;
    for (int f = 1; f < l; ++f) {
      const float scale = (2*f == nh) ? 1.f : 2.f;
      const float c2 = cv * scale, s2 = sv * scale;
#pragma unroll
      for (int i = 0; i < 16; ++i) {
        const float4 g = GL[f*17 + i];
        ud[i] += g.x*c2 - g.y*s2;
        us[i] += g.z*c2 - g.w*s2;
      }
      const float nc = cv*c1 - sv*s1, ns = sv*c1 + cv*s1;
      cv = nc; sv = ns;
    }
    const float invn = 1.f / (float)nh;
    const size_t ro = ((size_t)(b*nh + t)) * CKd;
    float4* pu = reinterpret_cast<float4*>(Ud + ro);
    float4* pv = reinterpret_cast<float4*>(Us + ro);
#pragma unroll
    for (int q = 0; q < 4; ++q) {
      pu[q] = make_float4(ud[q*4]*invn, ud[q*4+1]*invn, ud[q*4+2]*invn, ud[q*4+3]*invn);
      pv[q] = make_float4(us[q*4]*invn, us[q*4+1]*invn, us[q*4+2]*invn, us[q*4+3]*invn);
    }
  }
}

// ===========================================================================
// t0 / recon (proven).
// ===========================================================================
__global__ void t0_kernel(const float* __restrict__ xin, float* __restrict__ xout,
                          const float* __restrict__ t0w, const float* __restrict__ t0b)
{
  const int idx = blockIdx.x * 256 + threadIdx.x;
  if (idx >= BB * CKd) return;
  const int bc = idx >> 2;
  const int k  = idx & 3;
  float acc = t0b[k];
#pragma unroll
  for (int j = 0; j < 4; ++j) acc += xin[bc*4 + j] * t0w[k*4 + j];
  xout[idx] = acc;
}

__global__ __launch_bounds__(256) void recon_kernel(
    const float* __restrict__ xin, const float* __restrict__ UsL,
    const float* __restrict__ UdL, float* __restrict__ xout,
    int n, int lg, const float* __restrict__ rc_e, const float* __restrict__ rc_o)
{
  const int idx = blockIdx.x * 256 + threadIdx.x;
  if (idx >= BB * n) return;
  const int b = idx >> lg;
  const int t = idx & (n - 1);
  const size_t ro = ((size_t)b * n + t) * CKd;
  float xv[16], uv[16], dv[16];
#pragma unroll
  for (int q = 0; q < 4; ++q) {
    const float4 a = reinterpret_cast<const float4*>(xin + ro)[q];
    const float4 u = reinterpret_cast<const float4*>(UsL + ro)[q];
    const float4 d = reinterpret_cast<const float4*>(UdL + ro)[q];
    xv[q*4]=a.x; xv[q*4+1]=a.y; xv[q*4+2]=a.z; xv[q*4+3]=a.w;
    uv[q*4]=u.x; uv[q*4+1]=u.y; uv[q*4+2]=u.z; uv[q*4+3]=u.w;
    dv[q*4]=d.x; dv[q*4+1]=d.y; dv[q*4+2]=d.z; dv[q*4+3]=d.w;
  }
  float xe[16], xo[16];
#pragma unroll
  for (int c = 0; c < 4; ++c) {
    float xc[8];
#pragma unroll
    for (int m = 0; m < 4; ++m) { xc[m] = xv[c*4+m] + uv[c*4+m]; xc[4+m] = dv[c*4+m]; }
#pragma unroll
    for (int k = 0; k < 4; ++k) {
      float ae = 0.f, ao = 0.f;
#pragma unroll
      for (int m = 0; m < 8; ++m) { ae += xc[m] * rc_e[m*4+k]; ao += xc[m] * rc_o[m*4+k]; }
      xe[c*4+k] = ae; xo[c*4+k] = ao;
    }
  }
  float4* out = reinterpret_cast<float4*>(xout + ((size_t)b * (2*(size_t)n) + 2*(size_t)t) * CKd);
#pragma unroll
  for (int q = 0; q < 4; ++q) {
    out[q]   = make_float4(xe[q*4], xe[q*4+1], xe[q*4+2], xe[q*4+3]);
    out[4+q] = make_float4(xo[q*4], xo[q*4+1], xo[q*4+2], xo[q*4+3]);
  }
}

// ---------------------------------------------------------------------------
extern "C" void kernel_launch(void* const* d_in, const int* in_sizes, int n_in,
                              void* d_out, int out_size, void* d_ws, size_t ws_size,
                              hipStream_t stream)
{
  const float* x    = (const float*)d_in[0];
  const float* ec_s = (const float*)d_in[1];
  const float* ec_d = (const float*)d_in[2];
  const float* rc_e = (const float*)d_in[3];
  const float* rc_o = (const float*)d_in[4];
  const float* t0w  = (const float*)d_in[5];
  const float* t0b  = (const float*)d_in[6];
  const float* wAre = (const float*)d_in[7];
  const float* wAim = (const float*)d_in[8];
  const float* wBre = (const float*)d_in[9];
  const float* wBim = (const float*)d_in[10];
  const float* wCre = (const float*)d_in[11];
  const float* wCim = (const float*)d_in[12];

  float* ws = (float*)d_ws;
  const size_t XS_ELEMS = (size_t)BB * (NTOT/2) * CKd;   // 4,194,304
  const size_t U_ELEMS  = (size_t)BB * (NTOT - 1) * CKd; // 8,388,096
  const size_t F_ELEMS  = (size_t)BB * CKd * 64 * 2;     // 65,536
  float* xsA = ws;
  float* xsB = xsA + XS_ELEMS;
  float* UdS = xsB + XS_ELEMS;
  float* UsS = UdS + U_ELEMS;
  float* Fd  = UsS + U_ELEMS;
  float* Fx  = Fd + F_ELEMS;
  float* G4  = Fx + F_ELEMS;                             // 2*F_ELEMS floats

  float* udl[NLEV]; float* usl[NLEV]; int nlv[NLEV];

  // single upfront zero of the atomic targets; mix2 re-zeros per big level
  hipMemsetAsync(Fd, 0, 2 * F_ELEMS * sizeof(float), stream);

  // ---- decomposition ----
  const float* cur = x;
  float* nxt = xsA;
  size_t uoff = 0;
  int nhalf = NTOT / 2;
  for (int j = 0; j < NLEV; ++j, nhalf >>= 1) {
    const int l = (nhalf/2 + 1 < 64) ? (nhalf/2 + 1) : 64;
    udl[j] = UdS + uoff; usl[j] = UsS + uoff; nlv[j] = nhalf;
    if (nhalf >= 512) {
      fwd_big<<<dim3(BB, nhalf/256), 256, 0, stream>>>(cur, nxt, Fd, Fx, ec_s, ec_d, nhalf);
      mix2_kernel<<<BB, 256, 0, stream>>>(Fd, Fx, G4,
                                          wAre, wAim, wBre, wBim, wCre, wCim);
      inv_big<<<dim3(BB, nhalf/256), 256, 0, stream>>>(G4, udl[j], usl[j], nhalf);
    } else {
      small_level<<<BB, 256, 0, stream>>>(cur, nxt, udl[j], usl[j], ec_s, ec_d,
                                          wAre, wAim, wBre, wBim, wCre, wCim,
                                          nhalf, l);
    }
    uoff += (size_t)BB * nhalf * CKd;
    cur = nxt;
    nxt = (nxt == xsA) ? xsB : xsA;
  }

  // ---- coarsest-scale T0 ----
  t0_kernel<<<2, 256, 0, stream>>>(cur, nxt, t0w, t0b);
  cur = nxt;
  nxt = (nxt == xsA) ? xsB : xsA;

  // ---- reconstruction ----
  for (int i = NLEV - 1; i >= 0; --i) {
    const int n = nlv[i];
    int lg = 0; while ((1 << lg) < n) ++lg;
    float* out = (i == 0) ? (float*)d_out : nxt;
    const int total = BB * n;
    recon_kernel<<<(total + 255) / 256, 256, 0, stream>>>(cur, usl[i], udl[i], out,
                                                          n, lg, rc_e, rc_o);
    cur = out;
    nxt = (nxt == xsA) ? xsB : xsA;
  }
}